// Round 4
// baseline (768.732 us; speedup 1.0000x reference)
//
#include <hip/hip_runtime.h>
#include <stdint.h>
#include <math.h>

typedef unsigned short ushort_t;
typedef short short8 __attribute__((ext_vector_type(8)));
typedef float f32x4 __attribute__((ext_vector_type(4)));

__device__ __forceinline__ float b2f(ushort_t u) {
  union { uint32_t i; float f; } v; v.i = ((uint32_t)u) << 16; return v.f;
}
__device__ __forceinline__ ushort_t f2b(float f) {
  union { float f; uint32_t i; } v; v.f = f;
  uint32_t r = (v.i + 0x7FFFu + ((v.i >> 16) & 1u)) >> 16;
  return (ushort_t)r;
}

// global -> LDS async copy, 16B per lane. LDS dest must be uniform-base + lane*16.
__device__ __forceinline__ void gload16(const void* g, void* l) {
  __builtin_amdgcn_global_load_lds(
      (const __attribute__((address_space(1))) void*)(uintptr_t)g,
      (__attribute__((address_space(3))) void*)(uint32_t)(uintptr_t)l,
      16, 0, 0);
}

// ---------------------------------------------------------------- cast kernels
__global__ void cast_f32_bf16(const float* __restrict__ src, ushort_t* __restrict__ dst, long n) {
  long stride = (long)gridDim.x * blockDim.x;
  for (long i = (long)blockIdx.x * blockDim.x + threadIdx.x; i * 8 < n; i += stride) {
    const float4* s = (const float4*)(src + i * 8);
    float4 a = s[0], b = s[1];
    short8 o;
    o[0] = (short)f2b(a.x); o[1] = (short)f2b(a.y); o[2] = (short)f2b(a.z); o[3] = (short)f2b(a.w);
    o[4] = (short)f2b(b.x); o[5] = (short)f2b(b.y); o[6] = (short)f2b(b.z); o[7] = (short)f2b(b.w);
    *(short8*)(dst + i * 8) = o;
  }
}

// src fp32 [NB][Q][P] -> dst bf16 [NB][Qpad][Ppad], zero-padded.
__global__ void cast_pad_w(const float* __restrict__ src, ushort_t* __restrict__ dst,
                           int NB, int Q, int P, int Qpad, int Ppad) {
  long total = (long)NB * Qpad * Ppad;
  for (long i = (long)blockIdx.x * blockDim.x + threadIdx.x; i < total;
       i += (long)gridDim.x * blockDim.x) {
    int p = (int)(i % Ppad);
    long t = i / Ppad;
    int q = (int)(t % Qpad);
    int b = (int)(t / Qpad);
    float v = (q < Q && p < P) ? src[((long)b * Q + q) * P + p] : 0.f;
    dst[i] = f2b(v);
  }
}

// ---------------------------------------------------------------- GEMM
// C = A * W^T per z-block (W given row-major [Npad][Ppad] = B^T), bf16 in, fp32 acc.
// Double-buffered K-loop: stage tile t+1 into buf^1 BEFORE computing tile t from buf;
// single __syncthreads per step (its vmcnt(0)+lgkmcnt(0) drain is the prefetch wait).
// 1-D grid with XCD-aware swizzle (grid count must be %8==0), decoded x-fastest.
// MODE 0: scatter-store monarch permutation into 4 planes: f = z*Q+q -> plane f&3, col f>>2.
// MODE 1: bias + ReLU, store bf16 at out[row*ldout + z*Spad + s] for s < Q.
#define BM 128
#define BN 128
#define BK 64

template <int MODE>
__global__ __launch_bounds__(256, 2)
void gemm_bt(const ushort_t* __restrict__ A, int lda, long aZ,
             const ushort_t* __restrict__ W, int Npad, int Ppad, int K,
             const float* __restrict__ bias,
             ushort_t* __restrict__ out,
             int Q, int Rpad, long planeElems, int Spad, int ldout,
             int gx, int gy) {
  __shared__ __align__(16) ushort_t As[2][BM * BK];
  __shared__ __align__(16) ushort_t Bs[2][BN * BK];
  const int tid = threadIdx.x;
  const int lane = tid & 63;
  const int wave = tid >> 6;
  const int wm = wave >> 1, wn = wave & 1;

  // XCD-aware swizzle: hardware round-robins blockIdx.x over 8 XCDs; give each
  // XCD a contiguous chunk of logical tiles so the shared W-tiles stay in its L2.
  const int nb = gridDim.x;
  const int bid = blockIdx.x;
  const int swz = (bid & 7) * (nb >> 3) + (bid >> 3);
  const int bx = swz % gx;
  const int rest = swz / gx;
  const int by = rest % gy;
  const int z = rest / gy;

  const long m0 = (long)bx * BM;
  const int n0 = by * BN;

  const ushort_t* Ab = A + (long)z * aZ + m0 * lda;
  const ushort_t* Wb = W + (long)z * Npad * Ppad + (long)n0 * Ppad;

  f32x4 acc[4][4] = {};

  const int nsteps = K / BK;

  // stage K-tile `kt` into buffer `b`: 128 rows x 64 cols bf16 per matrix,
  // 1024 chunks of 16B each (4 per thread per matrix).
  auto stage = [&](int b, int kt) {
#pragma unroll
    for (int i = 0; i < 4; ++i) {
      int ch = tid + i * 256;
      int r = ch >> 3;
      int c = (ch & 7) * 8;
      gload16(Ab + (long)r * lda + kt + c, &As[b][ch * 8]);
      gload16(Wb + (long)r * Ppad + kt + c, &Bs[b][ch * 8]);
    }
  };

  stage(0, 0);
  __syncthreads();  // drains vmcnt(0): buf0 landed

  for (int it = 0; it < nsteps; ++it) {
    const int cur = it & 1;
    if (it + 1 < nsteps) stage(cur ^ 1, (it + 1) * BK);  // prefetch next tile

#pragma unroll
    for (int kk = 0; kk < 2; ++kk) {
      short8 af[4], bf[4];
#pragma unroll
      for (int mi = 0; mi < 4; ++mi) {
        int row = wm * 64 + mi * 16 + (lane & 15);
        af[mi] = *(const short8*)&As[cur][row * 64 + kk * 32 + ((lane >> 4) << 3)];
      }
#pragma unroll
      for (int nj = 0; nj < 4; ++nj) {
        int row = wn * 64 + nj * 16 + (lane & 15);
        bf[nj] = *(const short8*)&Bs[cur][row * 64 + kk * 32 + ((lane >> 4) << 3)];
      }
#pragma unroll
      for (int mi = 0; mi < 4; ++mi)
#pragma unroll
        for (int nj = 0; nj < 4; ++nj)
          acc[mi][nj] = __builtin_amdgcn_mfma_f32_16x16x32_bf16(af[mi], bf[nj], acc[mi][nj], 0, 0, 0);
    }
    __syncthreads();  // drains vmcnt(0) (prefetch landed) + lgkm; frees cur for overwrite
  }

  const int fq = lane >> 4;   // C/D: row = fq*4 + reg
  const int fr = lane & 15;   // C/D: col = fr
  if constexpr (MODE == 0) {
#pragma unroll
    for (int nj = 0; nj < 4; ++nj) {
      int q = n0 + wn * 64 + nj * 16 + fr;
      if (q < Q) {
        int f = z * Q + q;
        ushort_t* op = out + (long)(f & 3) * planeElems + (f >> 2);
#pragma unroll
        for (int mi = 0; mi < 4; ++mi) {
          long row = m0 + wm * 64 + mi * 16 + fq * 4;
#pragma unroll
          for (int j = 0; j < 4; ++j)
            op[(row + j) * (long)Rpad] = f2b(acc[mi][nj][j]);
        }
      }
    }
  } else {
#pragma unroll
    for (int nj = 0; nj < 4; ++nj) {
      int s = n0 + wn * 64 + nj * 16 + fr;
      if (s < Q) {
        float bv = bias[z * Q + s];
        ushort_t* op = out + (long)z * Spad + s;
#pragma unroll
        for (int mi = 0; mi < 4; ++mi) {
          long row = m0 + wm * 64 + mi * 16 + fq * 4;
#pragma unroll
          for (int j = 0; j < 4; ++j) {
            float v = acc[mi][nj][j] + bv;
            v = v > 0.f ? v : 0.f;
            op[(row + j) * (long)ldout] = f2b(v);
          }
        }
      }
    }
  }
}

// ---------------------------------------------------------------- layer 4 + log_softmax
// h3: [16384][128] bf16, blocks k at col k*32, p<25 valid.
__global__ __launch_bounds__(256)
void l4_softmax(const ushort_t* __restrict__ h3,
                const float* __restrict__ w14, const float* __restrict__ w24,
                const float* __restrict__ b4, float* __restrict__ outp) {
  __shared__ float w14s[300], w24s[36], b4s[10];
  int tid = threadIdx.x;
  for (int i = tid; i < 300; i += 256) w14s[i] = w14[i];
  if (tid < 36) w24s[tid] = w24[tid];
  if (tid < 10) b4s[tid] = b4[tid];
  __syncthreads();

  long row = (long)blockIdx.x * 256 + tid;
  const ushort_t* hr = h3 + row * 128;

  float a4[12];
#pragma unroll
  for (int k = 0; k < 4; ++k) {
    float hx[25];
#pragma unroll
    for (int p = 0; p < 25; ++p) hx[p] = b2f(hr[k * 32 + p]);
#pragma unroll
    for (int q = 0; q < 3; ++q) {
      float s = 0.f;
#pragma unroll
      for (int p = 0; p < 25; ++p) s += hx[p] * w14s[(k * 3 + q) * 25 + p];
      a4[k * 3 + q] = s;
    }
  }
  // monarch perm: f = k*3+q ; (l = f&3, r = f>>2); out2[l][s] = sum_r w24[l][s][r]*v[4r+l]
  float logit[10];
#pragma unroll
  for (int l = 0; l < 4; ++l) {
#pragma unroll
    for (int s = 0; s < 3; ++s) {
      int j = l * 3 + s;
      if (j < 10) {
        float v = 0.f;
#pragma unroll
        for (int r = 0; r < 3; ++r) v += w24s[(l * 3 + s) * 3 + r] * a4[4 * r + l];
        logit[j] = v + b4s[j];
      }
    }
  }
  float m = logit[0];
#pragma unroll
  for (int j = 1; j < 10; ++j) m = fmaxf(m, logit[j]);
  float sum = 0.f;
#pragma unroll
  for (int j = 0; j < 10; ++j) sum += expf(logit[j] - m);
  float lse = m + logf(sum);
#pragma unroll
  for (int j = 0; j < 10; ++j) outp[row * 10 + j] = logit[j] - lse;
}

// ---------------------------------------------------------------- launch
extern "C" void kernel_launch(void* const* d_in, const int* in_sizes, int n_in,
                              void* d_out, int out_size, void* d_ws, size_t ws_size,
                              hipStream_t stream) {
  (void)in_sizes; (void)n_in; (void)out_size; (void)ws_size;
  const float* x   = (const float*)d_in[0];
  const float* w11 = (const float*)d_in[1];
  const float* w21 = (const float*)d_in[2];
  const float* b1  = (const float*)d_in[3];
  const float* w12 = (const float*)d_in[4];
  const float* w22 = (const float*)d_in[5];
  const float* b2  = (const float*)d_in[6];
  const float* w13 = (const float*)d_in[7];
  const float* w23 = (const float*)d_in[8];
  const float* b3  = (const float*)d_in[9];
  const float* w14 = (const float*)d_in[10];
  const float* w24 = (const float*)d_in[11];
  const float* b4  = (const float*)d_in[12];
  float* out = (float*)d_out;
  char* ws = (char*)d_ws;

  // ws layout (bytes); t2/h2/t3/h3 alias the xb region (xb dead after L1A)
  ushort_t* w1b1 = (ushort_t*)(ws + 0);           // 4x768x768   bf16
  ushort_t* w2b1 = (ushort_t*)(ws + 4718592);     // 4x768x768
  ushort_t* w1b2 = (ushort_t*)(ws + 9437184);     // 4x256x768
  ushort_t* w2b2 = (ushort_t*)(ws + 11010048);    // 4x256x256
  ushort_t* w13b = (ushort_t*)(ws + 11534336);    // 4x128x256
  ushort_t* w23b = (ushort_t*)(ws + 11796480);    // 4x128x64
  const long OFF_XB = 11862016;
  ushort_t* xb = (ushort_t*)(ws + OFF_XB);                   // 16384x3072
  ushort_t* t2 = (ushort_t*)(ws + OFF_XB);                   // [4][16384][256]
  ushort_t* h2 = (ushort_t*)(ws + OFF_XB + 33554432);        // 16384x1024
  ushort_t* t3 = (ushort_t*)(ws + OFF_XB + 67108864);        // [4][16384][64]
  ushort_t* h3 = (ushort_t*)(ws + OFF_XB + 75497472);        // 16384x128
  ushort_t* t1 = (ushort_t*)(ws + 112525312);                // [4][16384][768]
  ushort_t* h1 = (ushort_t*)(ws + 213188608);                // 16384x3072

  cast_f32_bf16<<<4096, 256, 0, stream>>>(x, xb, 50331648L);
  cast_pad_w<<<2048, 256, 0, stream>>>(w11, w1b1, 4, 750, 768, 768, 768);
  cast_pad_w<<<2048, 256, 0, stream>>>(w21, w2b1, 4, 750, 750, 768, 768);
  cast_pad_w<<<1024, 256, 0, stream>>>(w12, w1b2, 4, 250, 750, 256, 768);
  cast_pad_w<<<512, 256, 0, stream>>>(w22, w2b2, 4, 250, 250, 256, 256);
  cast_pad_w<<<256, 256, 0, stream>>>(w13, w13b, 4, 25, 250, 128, 256);
  cast_pad_w<<<128, 256, 0, stream>>>(w23, w23b, 4, 25, 25, 128, 64);

  // L1: x(16384x3072) -> t1 planes -> h1(16384x3072 padded, blocks of 768, 750 valid)
  gemm_bt<0><<<128 * 6 * 4, 256, 0, stream>>>(xb, 3072, 768L, w1b1, 768, 768, 768,
                                              nullptr, t1, 750, 768, 16384L * 768, 0, 0, 128, 6);
  gemm_bt<1><<<128 * 6 * 4, 256, 0, stream>>>(t1, 768, 16384L * 768, w2b1, 768, 768, 768,
                                              b1, h1, 750, 0, 0, 768, 3072, 128, 6);
  // L2: h1 -> t2 planes -> h2(16384x1024 padded, blocks of 256, 250 valid)
  gemm_bt<0><<<128 * 2 * 4, 256, 0, stream>>>(h1, 3072, 768L, w1b2, 256, 768, 768,
                                              nullptr, t2, 250, 256, 16384L * 256, 0, 0, 128, 2);
  gemm_bt<1><<<128 * 2 * 4, 256, 0, stream>>>(t2, 256, 16384L * 256, w2b2, 256, 256, 256,
                                              b2, h2, 250, 0, 0, 256, 1024, 128, 2);
  // L3: h2 -> t3 planes -> h3(16384x128 padded, blocks of 32, 25 valid)
  gemm_bt<0><<<128 * 1 * 4, 256, 0, stream>>>(h2, 1024, 256L, w13b, 128, 256, 256,
                                              nullptr, t3, 25, 64, 16384L * 64, 0, 0, 128, 1);
  gemm_bt<1><<<128 * 1 * 4, 256, 0, stream>>>(t3, 64, 16384L * 64, w23b, 128, 64, 64,
                                              b3, h3, 25, 0, 0, 32, 128, 128, 1);
  // L4 + log_softmax
  l4_softmax<<<64, 256, 0, stream>>>(h3, w14, w24, b4, out);
}

// Round 6
// 700.685 us; speedup vs baseline: 1.0971x; 1.0971x over previous
//
#include <hip/hip_runtime.h>
#include <stdint.h>
#include <math.h>

typedef unsigned short ushort_t;
typedef short short8 __attribute__((ext_vector_type(8)));
typedef float f32x4 __attribute__((ext_vector_type(4)));

__device__ __forceinline__ float b2f(ushort_t u) {
  union { uint32_t i; float f; } v; v.i = ((uint32_t)u) << 16; return v.f;
}
__device__ __forceinline__ ushort_t f2b(float f) {
  union { float f; uint32_t i; } v; v.f = f;
  uint32_t r = (v.i + 0x7FFFu + ((v.i >> 16) & 1u)) >> 16;
  return (ushort_t)r;
}

// global -> LDS async copy, 16B per lane. LDS dest must be uniform-base + lane*16.
__device__ __forceinline__ void gload16(const void* g, void* l) {
  __builtin_amdgcn_global_load_lds(
      (const __attribute__((address_space(1))) void*)(uintptr_t)g,
      (__attribute__((address_space(3))) void*)(uint32_t)(uintptr_t)l,
      16, 0, 0);
}

// ---- 16B-chunk XOR swizzle for [256][32] bf16 LDS tiles (1KB blocks of 16 rows).
// logical chunk (row r, chunk-col c in 0..3) -> physical chunk index.
// Frag reads (r=base+lane&15, c=lane>>4) touch all 64 chunks of one block once:
// zero bank conflicts. Involution pair: stage uses inv_chunk on the SOURCE
// address (rule #21: linear LDS dest + inverse-swizzled global src + swizzled read).
__device__ __forceinline__ int swz_chunk(int r, int c) {
  int rp = (r >> 1) & 7;
  int s8 = ((r & 1) << 2) | c;
  return ((r >> 4) << 6) | (rp << 3) | (s8 ^ rp);
}
__device__ __forceinline__ void inv_chunk(int p, int& r, int& c) {
  int rp = (p >> 3) & 7, ps = p & 7, s8 = ps ^ rp;
  r = ((p >> 6) << 4) | (rp << 1) | (s8 >> 2);
  c = s8 & 3;
}

// ---------------------------------------------------------------- cast kernels
__global__ void cast_f32_bf16(const float* __restrict__ src, ushort_t* __restrict__ dst, long n) {
  long stride = (long)gridDim.x * blockDim.x;
  for (long i = (long)blockIdx.x * blockDim.x + threadIdx.x; i * 8 < n; i += stride) {
    const float4* s = (const float4*)(src + i * 8);
    float4 a = s[0], b = s[1];
    short8 o;
    o[0] = (short)f2b(a.x); o[1] = (short)f2b(a.y); o[2] = (short)f2b(a.z); o[3] = (short)f2b(a.w);
    o[4] = (short)f2b(b.x); o[5] = (short)f2b(b.y); o[6] = (short)f2b(b.z); o[7] = (short)f2b(b.w);
    *(short8*)(dst + i * 8) = o;
  }
}

// src fp32 [NB][Q][P] -> dst bf16 [NB][Qpad][Ppad], zero-padded.
__global__ void cast_pad_w(const float* __restrict__ src, ushort_t* __restrict__ dst,
                           int NB, int Q, int P, int Qpad, int Ppad) {
  long total = (long)NB * Qpad * Ppad;
  for (long i = (long)blockIdx.x * blockDim.x + threadIdx.x; i < total;
       i += (long)gridDim.x * blockDim.x) {
    int p = (int)(i % Ppad);
    long t = i / Ppad;
    int q = (int)(t % Qpad);
    int b = (int)(t / Qpad);
    float v = (q < Q && p < P) ? src[((long)b * Q + q) * P + p] : 0.f;
    dst[i] = f2b(v);
  }
}

// ---------------------------------------------------------------- ring GEMM (big shapes)
// C = A * W^T per z-block. 256x256 tile, BK=32, 512 threads (8 waves, 2M x 4N).
// 4-slot LDS ring (128KB): per step { vmcnt(8); barrier; stage kt+3 -> slot (kt+3)&3;
// 12 conflict-free ds_read_b128; setprio(1); 32 MFMA; setprio(0) }.
// Counted vmcnt keeps 3 tiles in flight; slot (kt+3)&3 == (kt-1)&3 was last read
// one barrier ago -> overwrite-safe. Ghost re-stages keep vmcnt uniform at tail.
// MODE 0: monarch scatter (f = z*Q+q -> plane f&3, col f>>2). MODE 1: bias+ReLU.
template <int MODE>
__global__ __launch_bounds__(512, 2)
void gemm_ring(const ushort_t* __restrict__ A, int lda, long aZ,
               const ushort_t* __restrict__ W, int Npad, int Ppad, int K,
               const float* __restrict__ bias,
               ushort_t* __restrict__ out,
               int Q, int Rpad, long planeElems, int Spad, int ldout) {
  __shared__ __align__(16) ushort_t lds[65536];  // 4 slots x (A 16KB + B 16KB)
  const int tid = threadIdx.x;
  const int lane = tid & 63;
  const int wave = tid >> 6;
  const int wm = wave >> 2;   // 0..1 : 128-row half
  const int wn = wave & 3;    // 0..3 : 64-col quarter
  const int z = blockIdx.z;
  const long m0 = (long)blockIdx.x * 256;
  const int n0 = blockIdx.y * 256;

  const ushort_t* Ab = A + (long)z * aZ + m0 * lda;
  const ushort_t* Wb = W + (long)z * Npad * Ppad + (long)n0 * Ppad;

  // per-thread stage coords: thread t writes physical chunks {t, t+512} of each
  // region (linear dest); source = global addr of the logical chunk there.
  int r0, c0, r1, c1;
  inv_chunk(tid, r0, c0);
  inv_chunk(tid + 512, r1, c1);
  const ushort_t* gA0 = Ab + (long)r0 * lda + c0 * 8;
  const ushort_t* gA1 = Ab + (long)r1 * lda + c1 * 8;
  const ushort_t* gB0 = Wb + (long)r0 * Ppad + c0 * 8;
  const ushort_t* gB1 = Wb + (long)r1 * Ppad + c1 * 8;

  // frag ds_read offsets (ushort units), swizzled; loop-invariant
  int offA[8], offB[4];
#pragma unroll
  for (int mi = 0; mi < 8; ++mi)
    offA[mi] = swz_chunk(wm * 128 + mi * 16 + (lane & 15), lane >> 4) * 8;
#pragma unroll
  for (int nj = 0; nj < 4; ++nj)
    offB[nj] = 8192 + swz_chunk(wn * 64 + nj * 16 + (lane & 15), lane >> 4) * 8;

  auto stage = [&](int slot, int kt) {
    long koff = (long)kt * 32;
    ushort_t* base = &lds[slot * 16384];
    gload16(gA0 + koff, base + tid * 8);
    gload16(gA1 + koff, base + 4096 + tid * 8);
    gload16(gB0 + koff, base + 8192 + tid * 8);
    gload16(gB1 + koff, base + 12288 + tid * 8);
  };

  const int nsteps = K / 32;
  stage(0, 0);
  stage(1, 1);
  stage(2, 2);

  f32x4 acc[8][4] = {};

  for (int kt = 0; kt < nsteps; ++kt) {
    // wait: 3 stages (12 loads) outstanding; oldest (tile kt) must be landed.
    asm volatile("s_waitcnt vmcnt(8)" ::: "memory");
    __builtin_amdgcn_s_barrier();
    int nx = kt + 3;
    if (nx >= nsteps) nx = nsteps - 1;        // ghost re-stage keeps count uniform
    stage((kt + 3) & 3, nx);

    const ushort_t* sl = &lds[(kt & 3) * 16384];
    short8 af[8], bf[4];
#pragma unroll
    for (int mi = 0; mi < 8; ++mi) af[mi] = *(const short8*)(sl + offA[mi]);
#pragma unroll
    for (int nj = 0; nj < 4; ++nj) bf[nj] = *(const short8*)(sl + offB[nj]);

    __builtin_amdgcn_s_setprio(1);
#pragma unroll
    for (int mi = 0; mi < 8; ++mi)
#pragma unroll
      for (int nj = 0; nj < 4; ++nj)
        acc[mi][nj] = __builtin_amdgcn_mfma_f32_16x16x32_bf16(af[mi], bf[nj], acc[mi][nj], 0, 0, 0);
    __builtin_amdgcn_s_setprio(0);
  }

  const int fq = lane >> 4;   // C/D: row = fq*4 + reg
  const int fr = lane & 15;   // C/D: col = fr
  if constexpr (MODE == 0) {
#pragma unroll
    for (int nj = 0; nj < 4; ++nj) {
      int q = n0 + wn * 64 + nj * 16 + fr;
      if (q < Q) {
        int f = z * Q + q;
        ushort_t* op = out + (long)(f & 3) * planeElems + (f >> 2);
#pragma unroll
        for (int mi = 0; mi < 8; ++mi) {
          long row = m0 + wm * 128 + mi * 16 + fq * 4;
#pragma unroll
          for (int j = 0; j < 4; ++j)
            op[(row + j) * (long)Rpad] = f2b(acc[mi][nj][j]);
        }
      }
    }
  } else {
#pragma unroll
    for (int nj = 0; nj < 4; ++nj) {
      int s = n0 + wn * 64 + nj * 16 + fr;
      if (s < Q) {
        float bv = bias[z * Q + s];
        ushort_t* op = out + (long)z * Spad + s;
#pragma unroll
        for (int mi = 0; mi < 8; ++mi) {
          long row = m0 + wm * 128 + mi * 16 + fq * 4;
#pragma unroll
          for (int j = 0; j < 4; ++j) {
            float v = acc[mi][nj][j] + bv;
            v = v > 0.f ? v : 0.f;
            op[(row + j) * (long)ldout] = f2b(v);
          }
        }
      }
    }
  }
}

// ---------------------------------------------------------------- small GEMM (round-1 structure)
#define BM 128
#define BN 128
#define BK 64

template <int MODE>
__global__ __launch_bounds__(256, 2)
void gemm_bt(const ushort_t* __restrict__ A, int lda, long aZ,
             const ushort_t* __restrict__ W, int Npad, int Ppad, int K,
             const float* __restrict__ bias,
             ushort_t* __restrict__ out,
             int Q, int Rpad, long planeElems, int Spad, int ldout) {
  __shared__ __align__(16) ushort_t As[BM * BK];
  __shared__ __align__(16) ushort_t Bs[BN * BK];
  const int tid = threadIdx.x;
  const int lane = tid & 63;
  const int wave = tid >> 6;
  const int wm = wave >> 1, wn = wave & 1;
  const int z = blockIdx.z;
  const long m0 = (long)blockIdx.x * BM;
  const int n0 = blockIdx.y * BN;

  const ushort_t* Ab = A + (long)z * aZ + m0 * lda;
  const ushort_t* Wb = W + (long)z * Npad * Ppad + (long)n0 * Ppad;

  f32x4 acc[4][4] = {};

  for (int kt = 0; kt < K; kt += BK) {
#pragma unroll
    for (int i = 0; i < 4; ++i) {
      int ch = tid + i * 256;
      int r = ch >> 3;
      int c = (ch & 7) * 8;
      gload16(Ab + (long)r * lda + kt + c, &As[ch * 8]);
      gload16(Wb + (long)r * Ppad + kt + c, &Bs[ch * 8]);
    }
    __syncthreads();
#pragma unroll
    for (int kk = 0; kk < 2; ++kk) {
      short8 af[4], bf[4];
#pragma unroll
      for (int mi = 0; mi < 4; ++mi) {
        int row = wm * 64 + mi * 16 + (lane & 15);
        af[mi] = *(const short8*)&As[row * 64 + kk * 32 + ((lane >> 4) << 3)];
      }
#pragma unroll
      for (int nj = 0; nj < 4; ++nj) {
        int row = wn * 64 + nj * 16 + (lane & 15);
        bf[nj] = *(const short8*)&Bs[row * 64 + kk * 32 + ((lane >> 4) << 3)];
      }
#pragma unroll
      for (int mi = 0; mi < 4; ++mi)
#pragma unroll
        for (int nj = 0; nj < 4; ++nj)
          acc[mi][nj] = __builtin_amdgcn_mfma_f32_16x16x32_bf16(af[mi], bf[nj], acc[mi][nj], 0, 0, 0);
    }
    __syncthreads();
  }

  const int fq = lane >> 4;
  const int fr = lane & 15;
  if constexpr (MODE == 0) {
#pragma unroll
    for (int nj = 0; nj < 4; ++nj) {
      int q = n0 + wn * 64 + nj * 16 + fr;
      if (q < Q) {
        int f = z * Q + q;
        ushort_t* op = out + (long)(f & 3) * planeElems + (f >> 2);
#pragma unroll
        for (int mi = 0; mi < 4; ++mi) {
          long row = m0 + wm * 64 + mi * 16 + fq * 4;
#pragma unroll
          for (int j = 0; j < 4; ++j)
            op[(row + j) * (long)Rpad] = f2b(acc[mi][nj][j]);
        }
      }
    }
  } else {
#pragma unroll
    for (int nj = 0; nj < 4; ++nj) {
      int s = n0 + wn * 64 + nj * 16 + fr;
      if (s < Q) {
        float bv = bias[z * Q + s];
        ushort_t* op = out + (long)z * Spad + s;
#pragma unroll
        for (int mi = 0; mi < 4; ++mi) {
          long row = m0 + wm * 64 + mi * 16 + fq * 4;
#pragma unroll
          for (int j = 0; j < 4; ++j) {
            float v = acc[mi][nj][j] + bv;
            v = v > 0.f ? v : 0.f;
            op[(row + j) * (long)ldout] = f2b(v);
          }
        }
      }
    }
  }
}

// ---------------------------------------------------------------- layer 4 + log_softmax
__global__ __launch_bounds__(256)
void l4_softmax(const ushort_t* __restrict__ h3,
                const float* __restrict__ w14, const float* __restrict__ w24,
                const float* __restrict__ b4, float* __restrict__ outp) {
  __shared__ float w14s[300], w24s[36], b4s[10];
  int tid = threadIdx.x;
  for (int i = tid; i < 300; i += 256) w14s[i] = w14[i];
  if (tid < 36) w24s[tid] = w24[tid];
  if (tid < 10) b4s[tid] = b4[tid];
  __syncthreads();

  long row = (long)blockIdx.x * 256 + tid;
  const ushort_t* hr = h3 + row * 128;

  float a4[12];
#pragma unroll
  for (int k = 0; k < 4; ++k) {
    float hx[25];
#pragma unroll
    for (int p = 0; p < 25; ++p) hx[p] = b2f(hr[k * 32 + p]);
#pragma unroll
    for (int q = 0; q < 3; ++q) {
      float s = 0.f;
#pragma unroll
      for (int p = 0; p < 25; ++p) s += hx[p] * w14s[(k * 3 + q) * 25 + p];
      a4[k * 3 + q] = s;
    }
  }
  float logit[10];
#pragma unroll
  for (int l = 0; l < 4; ++l) {
#pragma unroll
    for (int s = 0; s < 3; ++s) {
      int j = l * 3 + s;
      if (j < 10) {
        float v = 0.f;
#pragma unroll
        for (int r = 0; r < 3; ++r) v += w24s[(l * 3 + s) * 3 + r] * a4[4 * r + l];
        logit[j] = v + b4s[j];
      }
    }
  }
  float m = logit[0];
#pragma unroll
  for (int j = 1; j < 10; ++j) m = fmaxf(m, logit[j]);
  float sum = 0.f;
#pragma unroll
  for (int j = 0; j < 10; ++j) sum += expf(logit[j] - m);
  float lse = m + logf(sum);
#pragma unroll
  for (int j = 0; j < 10; ++j) outp[row * 10 + j] = logit[j] - lse;
}

// ---------------------------------------------------------------- launch
extern "C" void kernel_launch(void* const* d_in, const int* in_sizes, int n_in,
                              void* d_out, int out_size, void* d_ws, size_t ws_size,
                              hipStream_t stream) {
  (void)in_sizes; (void)n_in; (void)out_size; (void)ws_size;
  const float* x   = (const float*)d_in[0];
  const float* w11 = (const float*)d_in[1];
  const float* w21 = (const float*)d_in[2];
  const float* b1  = (const float*)d_in[3];
  const float* w12 = (const float*)d_in[4];
  const float* w22 = (const float*)d_in[5];
  const float* b2  = (const float*)d_in[6];
  const float* w13 = (const float*)d_in[7];
  const float* w23 = (const float*)d_in[8];
  const float* b3  = (const float*)d_in[9];
  const float* w14 = (const float*)d_in[10];
  const float* w24 = (const float*)d_in[11];
  const float* b4  = (const float*)d_in[12];
  float* out = (float*)d_out;
  char* ws = (char*)d_ws;

  // ws layout (bytes); t2/h2/t3/h3 alias the xb region (xb dead after L1A)
  ushort_t* w1b1 = (ushort_t*)(ws + 0);           // 4x768x768   bf16
  ushort_t* w2b1 = (ushort_t*)(ws + 4718592);     // 4x768x768
  ushort_t* w1b2 = (ushort_t*)(ws + 9437184);     // 4x256x768
  ushort_t* w2b2 = (ushort_t*)(ws + 11010048);    // 4x256x256
  ushort_t* w13b = (ushort_t*)(ws + 11534336);    // 4x128x256
  ushort_t* w23b = (ushort_t*)(ws + 11796480);    // 4x128x64
  const long OFF_XB = 11862016;
  ushort_t* xb = (ushort_t*)(ws + OFF_XB);                   // 16384x3072
  ushort_t* t2 = (ushort_t*)(ws + OFF_XB);                   // [4][16384][256]
  ushort_t* h2 = (ushort_t*)(ws + OFF_XB + 33554432);        // 16384x1024
  ushort_t* t3 = (ushort_t*)(ws + OFF_XB + 67108864);        // [4][16384][64]
  ushort_t* h3 = (ushort_t*)(ws + OFF_XB + 75497472);        // 16384x128
  ushort_t* t1 = (ushort_t*)(ws + 112525312);                // [4][16384][768]
  ushort_t* h1 = (ushort_t*)(ws + 213188608);                // 16384x3072

  cast_f32_bf16<<<4096, 256, 0, stream>>>(x, xb, 50331648L);
  cast_pad_w<<<2048, 256, 0, stream>>>(w11, w1b1, 4, 750, 768, 768, 768);
  cast_pad_w<<<2048, 256, 0, stream>>>(w21, w2b1, 4, 750, 750, 768, 768);
  cast_pad_w<<<1024, 256, 0, stream>>>(w12, w1b2, 4, 250, 750, 256, 768);
  cast_pad_w<<<512, 256, 0, stream>>>(w22, w2b2, 4, 250, 250, 256, 256);
  cast_pad_w<<<256, 256, 0, stream>>>(w13, w13b, 4, 25, 250, 128, 256);
  cast_pad_w<<<128, 256, 0, stream>>>(w23, w23b, 4, 25, 25, 128, 64);

  // L1: x(16384x3072) -> t1 planes -> h1 (ring kernel, 256^2 tiles)
  gemm_ring<0><<<dim3(64, 3, 4), 512, 0, stream>>>(xb, 3072, 768L, w1b1, 768, 768, 768,
                                                   nullptr, t1, 750, 768, 16384L * 768, 0, 0);
  gemm_ring<1><<<dim3(64, 3, 4), 512, 0, stream>>>(t1, 768, 16384L * 768, w2b1, 768, 768, 768,
                                                   b1, h1, 750, 0, 0, 768, 3072);
  // L2: h1 -> t2 planes -> h2
  gemm_ring<0><<<dim3(64, 1, 4), 512, 0, stream>>>(h1, 3072, 768L, w1b2, 256, 768, 768,
                                                   nullptr, t2, 250, 256, 16384L * 256, 0, 0);
  gemm_ring<1><<<dim3(64, 1, 4), 512, 0, stream>>>(t2, 256, 16384L * 256, w2b2, 256, 256, 256,
                                                   b2, h2, 250, 0, 0, 256, 1024);
  // L3: h2 -> t3 planes -> h3 (small N: round-1 kernel)
  gemm_bt<0><<<dim3(128, 1, 4), 256, 0, stream>>>(h2, 1024, 256L, w13b, 128, 256, 256,
                                                  nullptr, t3, 25, 64, 16384L * 64, 0, 0);
  gemm_bt<1><<<dim3(128, 1, 4), 256, 0, stream>>>(t3, 64, 16384L * 64, w23b, 128, 64, 64,
                                                  b3, h3, 25, 0, 0, 32, 128);
  // L4 + log_softmax
  l4_softmax<<<64, 256, 0, stream>>>(h3, w14, w24, b4, out);
}